// Round 5
// baseline (226.293 us; speedup 1.0000x reference)
//
#include <hip/hip_runtime.h>

// B=8, H=8, L=2048, D=64, num_delays=16
static constexpr int LSEQ = 2048;
static constexpr int NB   = 8;
static constexpr int NH   = 8;
static constexpr int ND   = 64;
static constexpr int NDEL = 16;

// ws layout (same 8.4 MB proven-safe envelope, same w/delay offsets):
//   Pc    : float2[128 part][8 b][1024]  at 0      (exactly 8 MiB)
//           compact partial spectra: slot j in [1,1024) holds freq j;
//           slot 0 packs (Re S[0], Re S[1024]) — both freqs are purely real.
//           After reduce_S, part 0 holds the reduced compact spectrum.
//   w     : float [8][16]               at 8388608
//   delay : int   [8][16]               at 8389120
static constexpr size_t WS_P_OFF     = 0;
static constexpr size_t WS_W_OFF     = 8388608;
static constexpr size_t WS_DELAY_OFF = 8389120;

// LDS bank swizzle on float2 index: fold bits 4..6 into bits 1..3.
__device__ __forceinline__ int SWZ(int x) { return x ^ (((x >> 4) & 7) << 1); }

// digit-reversed position of frequency f (radices 8,8,8,4 DIF) and inverse
__device__ __forceinline__ int pof(int f) {
    return ((f & 7) << 8) | (((f >> 3) & 7) << 5) | (((f >> 6) & 7) << 2) | (f >> 9);
}
__device__ __forceinline__ int fofp(int p) {
    return (p >> 8) | (((p >> 5) & 7) << 3) | (((p >> 2) & 7) << 6) | ((p & 3) << 9);
}

#define CMUL(ar, ai, br, bi) make_float2((ar)*(br) - (ai)*(bi), (ar)*(bi) + (ai)*(br))

__device__ __forceinline__ float2 cmulf(float2 a, float2 b) {
    return make_float2(a.x * b.x - a.y * b.y, a.x * b.y + a.y * b.x);
}

// 5-bit bit reversal (compile-time under unrolled loops)
__device__ __forceinline__ constexpr int BR5(int x) {
    return ((x & 1) << 4) | ((x & 2) << 2) | (x & 4) | ((x & 8) >> 2) | ((x & 16) >> 4);
}

// in-register DIF-32 (natural in, bit-reversed out: pos p holds A[BR5(p)])
// HW-verified in round-4's fft_corr (bench passed).
__device__ __forceinline__ void fft32_dif(float2 z[32]) {
    constexpr float WR[16] = {
        1.f,           0.980785280f,  0.923879533f,  0.831469612f,
        0.707106781f,  0.555570233f,  0.382683432f,  0.195090322f,
        0.f,          -0.195090322f, -0.382683432f, -0.555570233f,
       -0.707106781f, -0.831469612f, -0.923879533f, -0.980785280f };
    constexpr float WI[16] = {
       -0.f,          -0.195090322f, -0.382683432f, -0.555570233f,
       -0.707106781f, -0.831469612f, -0.923879533f, -0.980785280f,
       -1.f,          -0.980785280f, -0.923879533f, -0.831469612f,
       -0.707106781f, -0.555570233f, -0.382683432f, -0.195090322f };
    #pragma unroll
    for (int s = 0; s < 5; ++s) {
        const int hh = 16 >> s;
        #pragma unroll
        for (int b0 = 0; b0 < 32; b0 += 2 * hh) {
            #pragma unroll
            for (int u = 0; u < hh; ++u) {
                const float2 a = z[b0 + u], bb = z[b0 + u + hh];
                z[b0 + u] = make_float2(a.x + bb.x, a.y + bb.y);
                const float dx = a.x - bb.x, dy = a.y - bb.y;
                const int ti = u << s;                  // w_M^u = w_32^{u*2^s}
                z[b0 + u + hh] = (ti == 0) ? make_float2(dx, dy)
                    : make_float2(dx * WR[ti] - dy * WI[ti],
                                  dx * WI[ti] + dy * WR[ti]);
            }
        }
    }
}

// 8-pt DIF DFT in regs; x[0..7] in, X[0..7] (natural freq order) out.
__device__ __forceinline__ void dft8(const float2 x[8], float2 X[8]) {
    const float RH = 0.70710678118654752440f;
    float2 a0 = make_float2(x[0].x + x[4].x, x[0].y + x[4].y);
    float2 a1 = make_float2(x[1].x + x[5].x, x[1].y + x[5].y);
    float2 a2 = make_float2(x[2].x + x[6].x, x[2].y + x[6].y);
    float2 a3 = make_float2(x[3].x + x[7].x, x[3].y + x[7].y);
    float2 b0 = make_float2(x[0].x - x[4].x, x[0].y - x[4].y);
    float  t1r = x[1].x - x[5].x, t1i = x[1].y - x[5].y;
    float2 b1 = make_float2(RH * (t1r + t1i), RH * (t1i - t1r));       // * w8^1
    float  t2r = x[2].x - x[6].x, t2i = x[2].y - x[6].y;
    float2 b2 = make_float2(t2i, -t2r);                                // * -i
    float  t3r = x[3].x - x[7].x, t3i = x[3].y - x[7].y;
    float2 b3 = make_float2(RH * (t3i - t3r), -RH * (t3r + t3i));      // * w8^3
    float2 c0 = make_float2(a0.x + a2.x, a0.y + a2.y);
    float2 d0 = make_float2(a0.x - a2.x, a0.y - a2.y);
    float2 c1 = make_float2(a1.x + a3.x, a1.y + a3.y);
    float2 d1 = make_float2(a1.y - a3.y, -(a1.x - a3.x));              // * -i
    X[0] = make_float2(c0.x + c1.x, c0.y + c1.y);
    X[4] = make_float2(c0.x - c1.x, c0.y - c1.y);
    X[2] = make_float2(d0.x + d1.x, d0.y + d1.y);
    X[6] = make_float2(d0.x - d1.x, d0.y - d1.y);
    float2 e0 = make_float2(b0.x + b2.x, b0.y + b2.y);
    float2 f0 = make_float2(b0.x - b2.x, b0.y - b2.y);
    float2 e1 = make_float2(b1.x + b3.x, b1.y + b3.y);
    float2 f1 = make_float2(b1.y - b3.y, -(b1.x - b3.x));              // * -i
    X[1] = make_float2(e0.x + e1.x, e0.y + e1.y);
    X[5] = make_float2(e0.x - e1.x, e0.y - e1.y);
    X[3] = make_float2(f0.x + f1.x, f0.y + f1.y);
    X[7] = make_float2(f0.x - f1.x, f0.y - f1.y);
}

// 4-pt DFT: X[m] = sum_j x[j] (-i)^{jm}
__device__ __forceinline__ void dft4(const float2 x[4], float2 X[4]) {
    float2 s0 = make_float2(x[0].x + x[2].x, x[0].y + x[2].y);
    float2 s1 = make_float2(x[1].x + x[3].x, x[1].y + x[3].y);
    float2 d0 = make_float2(x[0].x - x[2].x, x[0].y - x[2].y);
    float2 d1 = make_float2(x[1].y - x[3].y, -(x[1].x - x[3].x));      // * -i
    X[0] = make_float2(s0.x + s1.x, s0.y + s1.y);
    X[2] = make_float2(s0.x - s1.x, s0.y - s1.y);
    X[1] = make_float2(d0.x + d1.x, d0.y + d1.y);
    X[3] = make_float2(d0.x - d1.x, d0.y - d1.y);
}

// in-place radix-8 stage with twiddle chain W on LDS plane zp
__device__ __forceinline__ void stageR8(float2* zp, const int adr[8], const float2 W[7]) {
    float2 X[8], Y[8];
    #pragma unroll
    for (int j = 0; j < 8; ++j) X[j] = zp[adr[j]];
    dft8(X, Y);
    #pragma unroll
    for (int m = 1; m < 8; ++m) Y[m] = CMUL(Y[m].x, Y[m].y, W[m-1].x, W[m-1].y);
    #pragma unroll
    for (int m = 0; m < 8; ++m) zp[adr[m]] = Y[m];
}

// final twiddle-free stage: two radix-4 on 8 consecutive; result also in X
__device__ __forceinline__ void stageD(float2* zp, const int adr[8], float2 X[8]) {
    float2 xin[8];
    #pragma unroll
    for (int j = 0; j < 8; ++j) xin[j] = zp[adr[j]];
    dft4(&xin[0], &X[0]);
    dft4(&xin[4], &X[4]);
    #pragma unroll
    for (int m = 0; m < 8; ++m) zp[adr[m]] = X[m];
}

// ---------------------------------------------------------------------------
// Kernel A: EXACT round-3 version (53 µs measured, no spill, VGPR 92).
// Block = (b,h,grp of 8 d-chan, half of 4). Mixed-radix 8*8*8*4 DIF FFT,
// TWO channels in flight per sync phase (two 16 KiB LDS planes). Grid 1024.
// Compact partial store (f in [0,1024), slot 0 packs real freqs 0 & 1024).
// (Round-4's shuffle-FFT variant regressed to 63 µs: __shfl_xor = ds_swizzle
// on the LDS pipe; 450 dependent DS ops/wave replaced barrier latency with
// DS-pipe latency. Reverted.)
// ---------------------------------------------------------------------------
__global__ __launch_bounds__(256, 2) void fft_corr(const float* __restrict__ q,
                                                   const float* __restrict__ k,
                                                   float2* __restrict__ Pc) {
    __shared__ float2 z0[LSEQ], z1[LSEQ];   // 32 KiB (swizzled)
    const int t    = threadIdx.x;
    const int bi   = blockIdx.x;            // 1024 = 8 xcd * 8 bh * 8 grp * 2 half
    const int xcd  = bi & 7;
    const int sl   = bi >> 3;               // 0..127
    const int bh   = xcd * 8 + (sl >> 4);   // 16 blocks of same bh share an XCD
    const int grp  = (sl >> 1) & 7;
    const int half = sl & 1;
    const int b    = bh >> 3;
    const int h    = bh & 7;
    const size_t base = (size_t)bh * LSEQ * ND + (size_t)(grp * 8 + half * 4);

    // twiddle power chains (per thread, shared by all channels)
    float2 WA[7], WB[7], WC[7];
    {
        float sn, cs;
        __sincosf(-6.28318530717958647692f * (float)t / 2048.f, &sn, &cs);
        WA[0] = make_float2(cs, sn);
        __sincosf(-6.28318530717958647692f * (float)(t & 31) / 256.f, &sn, &cs);
        WB[0] = make_float2(cs, sn);
        __sincosf(-6.28318530717958647692f * (float)(t & 3) / 32.f, &sn, &cs);
        WC[0] = make_float2(cs, sn);
        #pragma unroll
        for (int m = 1; m < 7; ++m) {
            WA[m] = CMUL(WA[m-1].x, WA[m-1].y, WA[0].x, WA[0].y);
            WB[m] = CMUL(WB[m-1].x, WB[m-1].y, WB[0].x, WB[0].y);
            WC[m] = CMUL(WC[m-1].x, WC[m-1].y, WC[0].x, WC[0].y);
        }
    }

    // owned product slots: cc in {0,1,4,5} -> f in [0,1024)
    int fS[4], pmS[4];
    #pragma unroll
    for (int s = 0; s < 4; ++s) {
        const int cc = (s < 2) ? s : s + 2;           // {0,1,4,5}
        const int f  = fofp(8 * t + cc);
        const int m  = (2048 - f) & 2047;
        fS[s]  = f;
        pmS[s] = SWZ(pof(m));
    }
    float aFr[4] = {0, 0, 0, 0}, aFi[4] = {0, 0, 0, 0};
    float aS = 0.f;                      // f=1024 special (thread 0)

    const int sbB   = (t >> 5) * 256 + (t & 31);
    const int baseC = (t >> 2) * 32 + (t & 3);
    int adrB[8], adrC[8], adrD[8];
    #pragma unroll
    for (int n = 0; n < 8; ++n) {
        adrB[n] = SWZ(sbB + 32 * n);
        adrC[n] = SWZ(baseC + 4 * n);
        adrD[n] = SWZ(8 * t + n);
    }

    float4 qa[8], ka[8];
    #pragma unroll
    for (int j = 0; j < 8; ++j) {
        const size_t r = base + (size_t)(t + 256 * j) * ND;
        qa[j] = *(const float4*)(q + r);
        ka[j] = *(const float4*)(k + r);
    }
    #pragma unroll
    for (int pr = 0; pr < 2; ++pr) {
        const int c0 = 2 * pr, c1 = 2 * pr + 1;
        float2 X0[8], X1[8], Y0[8], Y1[8];
        #pragma unroll
        for (int j = 0; j < 8; ++j) {
            X0[j] = make_float2((&qa[j].x)[c0], (&ka[j].x)[c0]);
            X1[j] = make_float2((&qa[j].x)[c1], (&ka[j].x)[c1]);
        }
        __syncthreads();             // z planes free (prev pair's readers done)

        // stage A: radix-8 on rows t+256j (from regs), scatter to bands
        dft8(X0, Y0);
        dft8(X1, Y1);
        #pragma unroll
        for (int m = 1; m < 8; ++m) {
            Y0[m] = CMUL(Y0[m].x, Y0[m].y, WA[m-1].x, WA[m-1].y);
            Y1[m] = CMUL(Y1[m].x, Y1[m].y, WA[m-1].x, WA[m-1].y);
        }
        #pragma unroll
        for (int m = 0; m < 8; ++m) {
            const int a = SWZ(m * 256 + t);
            z0[a] = Y0[m];
            z1[a] = Y1[m];
        }
        __syncthreads();

        stageR8(z0, adrB, WB);
        stageR8(z1, adrB, WB);
        __syncthreads();

        stageR8(z0, adrC, WC);
        stageR8(z1, adrC, WC);
        __syncthreads();

        stageD(z0, adrD, X0);
        stageD(z1, adrD, X1);
        __syncthreads();

        // product: acc Q[f] conj(K[f]) for 4 owned slots (+f=1024)
        #pragma unroll
        for (int s = 0; s < 4; ++s) {
            const int cc = (s < 2) ? s : s + 2;   // {0,1,4,5}
            {
                const float2 Zf = X0[cc], Zm = z0[pmS[s]];
                const float qr = 0.5f * (Zf.x + Zm.x), qi = 0.5f * (Zf.y - Zm.y);
                const float kr = 0.5f * (Zf.y + Zm.y), ki = 0.5f * (Zm.x - Zf.x);
                aFr[s] += qr * kr + qi * ki;
                aFi[s] += qi * kr - qr * ki;
            }
            {
                const float2 Zf = X1[cc], Zm = z1[pmS[s]];
                const float qr = 0.5f * (Zf.x + Zm.x), qi = 0.5f * (Zf.y - Zm.y);
                const float kr = 0.5f * (Zf.y + Zm.y), ki = 0.5f * (Zm.x - Zf.x);
                aFr[s] += qr * kr + qi * ki;
                aFi[s] += qi * kr - qr * ki;
            }
        }
        if (t == 0) aS += X0[2].x * X0[2].y + X1[2].x * X1[2].y;
    }

    // compact store: Pc[part][b][f] = acc, f = fS[s] in [0,1024).
    // slot 0 packs (Re S[0], Re S[1024]); Im S[0] is mathematically 0.
    const int part = h * 16 + grp * 2 + half;        // 0..127
    float2* Pp = Pc + (size_t)part * (NB * 1024) + (size_t)b * 1024;
    #pragma unroll
    for (int s = 0; s < 4; ++s) Pp[fS[s]] = make_float2(aFr[s], aFi[s]);
    if (t == 0) Pp[0] = make_float2(aFr[0], aS);
}

// ---------------------------------------------------------------------------
// Reduce 128 compact partials IN-PLACE into part 0. 128 blocks; each block
// owns 64 columns, 4 part-slices of 32 summed per thread then LDS tree.
// ---------------------------------------------------------------------------
__global__ __launch_bounds__(256) void reduce_S(float2* __restrict__ Pc) {
    __shared__ float2 acc[256];
    const int t     = threadIdx.x;
    const int col   = blockIdx.x * 64 + (t & 63);    // 0..8191 = b*1024+j
    const int slice = t >> 6;                        // 4 slices x 32 parts
    float ax = 0.f, ay = 0.f;
    #pragma unroll 8
    for (int pp = 0; pp < 32; ++pp) {
        const float2 v = Pc[(size_t)(slice * 32 + pp) * (NB * 1024) + col];
        ax += v.x; ay += v.y;
    }
    acc[t] = make_float2(ax, ay);
    __syncthreads();
    if (t < 64) {
        const float2 r0 = acc[t], r1 = acc[t + 64], r2 = acc[t + 128], r3 = acc[t + 192];
        Pc[col] = make_float2(r0.x + r1.x + r2.x + r3.x, r0.y + r1.y + r2.y + r3.y);
    }
}

// ---------------------------------------------------------------------------
// Kernel B (REWRITTEN): one 64-lane WAVE per batch, ZERO barriers, no LDS.
// Previous version: 8 blocks x 256 threads, ~37 barrier-separated phases
// (5 LDS FFT stages + 16 argmax rounds x 2 barriers) serialized on 8 CUs —
// prime suspect for the unprofiled ~140 µs residual.
// New: the whole 2048-pt forward FFT of conj(S) lives in 32 float2 regs/lane
// using round-4's HW-VERIFIED blocks (fft32_dif + twiddle chain + 6-stage
// shfl DIF; they passed the bench inside fft_corr). irfft(S)[tau] =
// Re(FFT_fwd(conj(S))[tau])/2048; output tau at (reg p, lane L) =
// BR5(p) + 32*br6(L). conj(S)[f] built straight from the compact spectrum
// with per-lane conj-symmetry folding (coalesced 8B loads). Top-16 = 16
// unrolled in-register argmax rounds (31-cmp reg tree + 6 shfl_xor), tie ->
// smaller tau, removal by tau-match (static reg indexing only — no scratch).
// ---------------------------------------------------------------------------
__global__ __launch_bounds__(64) void ifft_topk(const float2* __restrict__ S,
                                                float* __restrict__ wout,
                                                int* __restrict__ dout) {
    const int b = blockIdx.x;
    const int L = threadIdx.x;                         // lane 0..63
    const int k2 = (int)(__brev((unsigned)L) >> 26);   // br6(L)
    const int base32 = k2 << 5;

    // ---- build x[f] = conj(S)[f], f = 64*j + L, from compact spectrum ----
    float2 z[32];
    #pragma unroll
    for (int j = 0; j < 32; ++j) {
        const int f   = 64 * j + L;
        const int idx = (f < 1024) ? f : ((f == 1024) ? 0 : 2048 - f);
        const float2 s = S[b * 1024 + idx];
        float2 x;
        if (f == 0)         x = make_float2(s.x, 0.f);     // S[0] real
        else if (f == 1024) x = make_float2(s.y, 0.f);     // S[1024] real (packed)
        else if (f < 1024)  x = make_float2(s.x, -s.y);    // conj(S[f])
        else                x = make_float2(s.x,  s.y);    // conj(S[f]) = S[2048-f]
        z[j] = x;
    }

    // ---- step 1: in-lane DIF-32 ----
    fft32_dif(z);

    // ---- step 2: twiddle w_2048^{L*k1}, k1 = BR5(p) ----
    {
        float sn, cs;
        __sincosf(-6.28318530717958647692f * (float)L / 2048.f, &sn, &cs);
        const float2 W1 = make_float2(cs, sn);
        float2 Wc = W1;
        z[BR5(1)] = cmulf(z[BR5(1)], Wc);
        #pragma unroll
        for (int m = 2; m < 32; ++m) {
            Wc = cmulf(Wc, W1);
            z[BR5(m)] = cmulf(z[BR5(m)], Wc);
        }
    }

    // ---- step 3: cross-lane DIF-64 over lanes (6 shfl_xor stages) ----
    #pragma unroll
    for (int s = 0; s < 6; ++s) {
        const int hh = 32 >> s;
        float ts, tc;
        __sincosf(-6.28318530717958647692f * (float)(L & (hh - 1)) /
                      (float)(64 >> s), &ts, &tc);
        const bool bot = (L & hh) != 0;
        #pragma unroll
        for (int p = 0; p < 32; ++p) {
            const float ex = __shfl_xor(z[p].x, hh);
            const float ey = __shfl_xor(z[p].y, hh);
            const float ax = z[p].x + ex, ay = z[p].y + ey;
            const float sx = ex - z[p].x, sy = ey - z[p].y;
            const float bx = sx * tc - sy * ts;
            const float by = sx * ts + sy * tc;
            z[p].x = bot ? bx : ax;
            z[p].y = bot ? by : ay;
        }
    }

    // ---- mc values: val[p] = Re/(L*H*D), tau(p) = BR5(p) + base32 ----
    const float scale = 1.0f / ((float)LSEQ * (float)(NH * ND));
    float vals[32];
    #pragma unroll
    for (int p = 0; p < 32; ++p) vals[p] = z[p].x * scale;

    // ---- top-16 by iterative wave-wide argmax (ties -> smaller tau) ----
    float topv[NDEL]; int topi[NDEL];
    #pragma unroll
    for (int it = 0; it < NDEL; ++it) {
        float bv = -3e38f; int btau = 1 << 30;
        #pragma unroll
        for (int p = 0; p < 32; ++p) {
            const int tau = BR5(p) + base32;
            if (vals[p] > bv || (vals[p] == bv && tau < btau)) { bv = vals[p]; btau = tau; }
        }
        #pragma unroll
        for (int off = 32; off; off >>= 1) {
            const float ov = __shfl_xor(bv, off);
            const int   ot = __shfl_xor(btau, off);
            if (ov > bv || (ov == bv && ot < btau)) { bv = ov; btau = ot; }
        }
        topv[it] = bv; topi[it] = btau;
        #pragma unroll
        for (int p = 0; p < 32; ++p)
            if (BR5(p) + base32 == btau) vals[p] = -3e38f;   // remove winner
    }

    if (L == 0) {
        const float m = topv[0];
        float e[NDEL], sum = 0.f;
        #pragma unroll
        for (int i = 0; i < NDEL; ++i) { e[i] = __expf(topv[i] - m); sum += e[i]; }
        const float inv = 1.0f / sum;
        #pragma unroll
        for (int i = 0; i < NDEL; ++i) {
            wout[b * NDEL + i] = e[i] * inv;
            dout[b * NDEL + i] = topi[i];
        }
    }
}

// ---------------------------------------------------------------------------
// Kernel C: out[b,h,t,d] = sum_k w[b,k] * v[b,h,(t+delay[b,k]) & 2047, d]
// XCD swizzle: 128 t-tiles of one (b,h) share an XCD (v slice L2-resident).
// ---------------------------------------------------------------------------
__global__ __launch_bounds__(256) void gather_out(const float* __restrict__ v,
                                                  const float* __restrict__ w,
                                                  const int* __restrict__ delay,
                                                  float* __restrict__ out) {
    const int bi  = blockIdx.x;          // 8192 = 64 bh * 128 tiles
    const int xcd = bi & 7;
    const int s   = bi >> 3;
    const int bh  = xcd * 8 + (s >> 7);
    const int bt  = s & 127;
    const int b   = bh >> 3;
    const int tid = threadIdx.x;

    __shared__ float sw_[NDEL];
    __shared__ int   sd_[NDEL];
    if (tid < NDEL) {
        sw_[tid] = w[b * NDEL + tid];
        sd_[tid] = delay[b * NDEL + tid];
    }
    __syncthreads();

    const float* vb = v + (size_t)bh * LSEQ * ND;
    float*       ob = out + (size_t)bh * LSEQ * ND;

    const int row = tid >> 4;
    const int col = (tid & 15) * 4;
    const int t   = bt * 16 + row;

    float4 acc = make_float4(0.f, 0.f, 0.f, 0.f);
    #pragma unroll
    for (int kk = 0; kk < NDEL; ++kk) {
        const int r = (t + sd_[kk]) & (LSEQ - 1);
        const float4 vv = *(const float4*)(vb + (size_t)r * ND + col);
        const float wv = sw_[kk];
        acc.x += wv * vv.x; acc.y += wv * vv.y;
        acc.z += wv * vv.z; acc.w += wv * vv.w;
    }
    *(float4*)(ob + (size_t)t * ND + col) = acc;
}

// ---------------------------------------------------------------------------
extern "C" void kernel_launch(void* const* d_in, const int* in_sizes, int n_in,
                              void* d_out, int out_size, void* d_ws, size_t ws_size,
                              hipStream_t stream) {
    const float* q = (const float*)d_in[0];
    const float* k = (const float*)d_in[1];
    const float* v = (const float*)d_in[2];
    float* out = (float*)d_out;

    float2* Pc    = (float2*)((char*)d_ws + WS_P_OFF);
    float*  w     = (float*)((char*)d_ws + WS_W_OFF);
    int*    delay = (int*)((char*)d_ws + WS_DELAY_OFF);

    fft_corr<<<dim3(1024), dim3(256), 0, stream>>>(q, k, Pc);
    reduce_S<<<dim3(128), dim3(256), 0, stream>>>(Pc);
    ifft_topk<<<dim3(NB), dim3(64), 0, stream>>>(Pc, w, delay);   // part 0 = S
    gather_out<<<dim3(NB * NH * 128), dim3(256), 0, stream>>>(v, w, delay, out);
}

// Round 6
// 224.027 us; speedup vs baseline: 1.0101x; 1.0101x over previous
//
#include <hip/hip_runtime.h>

// B=8, H=8, L=2048, D=64, num_delays=16
static constexpr int LSEQ = 2048;
static constexpr int NB   = 8;
static constexpr int NH   = 8;
static constexpr int ND   = 64;
static constexpr int NDEL = 16;

// ws layout (same 8.4 MB proven-safe envelope, same w/delay offsets):
//   Pc    : float2[128 part][8 b][1024]  at 0      (exactly 8 MiB)
//           compact partial spectra: slot j in [1,1024) holds freq j;
//           slot 0 packs (Re S[0], Re S[1024]) — both freqs are purely real.
//           After reduce_S, part 0 holds the reduced compact spectrum.
//   w     : float [8][16]               at 8388608
//   delay : int   [8][16]               at 8389120
static constexpr size_t WS_P_OFF     = 0;
static constexpr size_t WS_W_OFF     = 8388608;
static constexpr size_t WS_DELAY_OFF = 8389120;

// LDS bank swizzle on float2 index: fold bits 4..6 into bits 1..3.
// NOTE: touches only bits 1..3 — band bits (8..10), 32-group bits (5..7)
// are preserved, which is what makes the intra-wave barrier elision legal.
__device__ __forceinline__ int SWZ(int x) { return x ^ (((x >> 4) & 7) << 1); }

// digit-reversed position of frequency f (radices 8,8,8,4 DIF) and inverse
__device__ __forceinline__ int pof(int f) {
    return ((f & 7) << 8) | (((f >> 3) & 7) << 5) | (((f >> 6) & 7) << 2) | (f >> 9);
}
__device__ __forceinline__ int fofp(int p) {
    return (p >> 8) | (((p >> 5) & 7) << 3) | (((p >> 2) & 7) << 6) | ((p & 3) << 9);
}

#define CMUL(ar, ai, br, bi) make_float2((ar)*(br) - (ai)*(bi), (ar)*(bi) + (ai)*(br))

__device__ __forceinline__ float2 cmulf(float2 a, float2 b) {
    return make_float2(a.x * b.x - a.y * b.y, a.x * b.y + a.y * b.x);
}

// 5-bit bit reversal (compile-time under unrolled loops)
__device__ __forceinline__ constexpr int BR5(int x) {
    return ((x & 1) << 4) | ((x & 2) << 2) | (x & 4) | ((x & 8) >> 2) | ((x & 16) >> 4);
}

// in-register DIF-32 (natural in, bit-reversed out: pos p holds A[BR5(p)])
// HW-verified in round-4's fft_corr (bench passed).
__device__ __forceinline__ void fft32_dif(float2 z[32]) {
    constexpr float WR[16] = {
        1.f,           0.980785280f,  0.923879533f,  0.831469612f,
        0.707106781f,  0.555570233f,  0.382683432f,  0.195090322f,
        0.f,          -0.195090322f, -0.382683432f, -0.555570233f,
       -0.707106781f, -0.831469612f, -0.923879533f, -0.980785280f };
    constexpr float WI[16] = {
       -0.f,          -0.195090322f, -0.382683432f, -0.555570233f,
       -0.707106781f, -0.831469612f, -0.923879533f, -0.980785280f,
       -1.f,          -0.980785280f, -0.923879533f, -0.831469612f,
       -0.707106781f, -0.555570233f, -0.382683432f, -0.195090322f };
    #pragma unroll
    for (int s = 0; s < 5; ++s) {
        const int hh = 16 >> s;
        #pragma unroll
        for (int b0 = 0; b0 < 32; b0 += 2 * hh) {
            #pragma unroll
            for (int u = 0; u < hh; ++u) {
                const float2 a = z[b0 + u], bb = z[b0 + u + hh];
                z[b0 + u] = make_float2(a.x + bb.x, a.y + bb.y);
                const float dx = a.x - bb.x, dy = a.y - bb.y;
                const int ti = u << s;                  // w_M^u = w_32^{u*2^s}
                z[b0 + u + hh] = (ti == 0) ? make_float2(dx, dy)
                    : make_float2(dx * WR[ti] - dy * WI[ti],
                                  dx * WI[ti] + dy * WR[ti]);
            }
        }
    }
}

// 8-pt DIF DFT in regs; x[0..7] in, X[0..7] (natural freq order) out.
__device__ __forceinline__ void dft8(const float2 x[8], float2 X[8]) {
    const float RH = 0.70710678118654752440f;
    float2 a0 = make_float2(x[0].x + x[4].x, x[0].y + x[4].y);
    float2 a1 = make_float2(x[1].x + x[5].x, x[1].y + x[5].y);
    float2 a2 = make_float2(x[2].x + x[6].x, x[2].y + x[6].y);
    float2 a3 = make_float2(x[3].x + x[7].x, x[3].y + x[7].y);
    float2 b0 = make_float2(x[0].x - x[4].x, x[0].y - x[4].y);
    float  t1r = x[1].x - x[5].x, t1i = x[1].y - x[5].y;
    float2 b1 = make_float2(RH * (t1r + t1i), RH * (t1i - t1r));       // * w8^1
    float  t2r = x[2].x - x[6].x, t2i = x[2].y - x[6].y;
    float2 b2 = make_float2(t2i, -t2r);                                // * -i
    float  t3r = x[3].x - x[7].x, t3i = x[3].y - x[7].y;
    float2 b3 = make_float2(RH * (t3i - t3r), -RH * (t3r + t3i));      // * w8^3
    float2 c0 = make_float2(a0.x + a2.x, a0.y + a2.y);
    float2 d0 = make_float2(a0.x - a2.x, a0.y - a2.y);
    float2 c1 = make_float2(a1.x + a3.x, a1.y + a3.y);
    float2 d1 = make_float2(a1.y - a3.y, -(a1.x - a3.x));              // * -i
    X[0] = make_float2(c0.x + c1.x, c0.y + c1.y);
    X[4] = make_float2(c0.x - c1.x, c0.y - c1.y);
    X[2] = make_float2(d0.x + d1.x, d0.y + d1.y);
    X[6] = make_float2(d0.x - d1.x, d0.y - d1.y);
    float2 e0 = make_float2(b0.x + b2.x, b0.y + b2.y);
    float2 f0 = make_float2(b0.x - b2.x, b0.y - b2.y);
    float2 e1 = make_float2(b1.x + b3.x, b1.y + b3.y);
    float2 f1 = make_float2(b1.y - b3.y, -(b1.x - b3.x));              // * -i
    X[1] = make_float2(e0.x + e1.x, e0.y + e1.y);
    X[5] = make_float2(e0.x - e1.x, e0.y - e1.y);
    X[3] = make_float2(f0.x + f1.x, f0.y + f1.y);
    X[7] = make_float2(f0.x - f1.x, f0.y - f1.y);
}

// 4-pt DFT: X[m] = sum_j x[j] (-i)^{jm}
__device__ __forceinline__ void dft4(const float2 x[4], float2 X[4]) {
    float2 s0 = make_float2(x[0].x + x[2].x, x[0].y + x[2].y);
    float2 s1 = make_float2(x[1].x + x[3].x, x[1].y + x[3].y);
    float2 d0 = make_float2(x[0].x - x[2].x, x[0].y - x[2].y);
    float2 d1 = make_float2(x[1].y - x[3].y, -(x[1].x - x[3].x));      // * -i
    X[0] = make_float2(s0.x + s1.x, s0.y + s1.y);
    X[2] = make_float2(s0.x - s1.x, s0.y - s1.y);
    X[1] = make_float2(d0.x + d1.x, d0.y + d1.y);
    X[3] = make_float2(d0.x - d1.x, d0.y - d1.y);
}

// in-place radix-8 stage with twiddle chain W on LDS plane zp
__device__ __forceinline__ void stageR8(float2* zp, const int adr[8], const float2 W[7]) {
    float2 X[8], Y[8];
    #pragma unroll
    for (int j = 0; j < 8; ++j) X[j] = zp[adr[j]];
    dft8(X, Y);
    #pragma unroll
    for (int m = 1; m < 8; ++m) Y[m] = CMUL(Y[m].x, Y[m].y, W[m-1].x, W[m-1].y);
    #pragma unroll
    for (int m = 0; m < 8; ++m) zp[adr[m]] = Y[m];
}

// final twiddle-free stage: two radix-4 on 8 consecutive; result also in X
__device__ __forceinline__ void stageD(float2* zp, const int adr[8], float2 X[8]) {
    float2 xin[8];
    #pragma unroll
    for (int j = 0; j < 8; ++j) xin[j] = zp[adr[j]];
    dft4(&xin[0], &X[0]);
    dft4(&xin[4], &X[4]);
    #pragma unroll
    for (int m = 0; m < 8; ++m) zp[adr[m]] = X[m];
}

// ---------------------------------------------------------------------------
// Kernel A: round-3 verified pipeline + BARRIER ELISION. Dataflow proof:
// after stage A's full scatter, band b (positions [256b,256b+256), band bits
// 8..10 preserved by SWZ) is read AND written exclusively by threads
// 32b..32b+31 through stages B (band t>>5), C (group t>>2 ⊂ band t>>5) and
// D (8t+n ⊂ band t>>5). One 32-thread cluster ⊂ one 64-lane wave, and
// same-wave DS ops execute in program order → the B→C and C→D
// __syncthreads are unnecessary. pr-loop hand-unrolled to also drop the
// block-entry barrier: 10 barriers/block → 5. Product's mirror reads cross
// bands → the D→product barrier stays; product→next-A reuse barrier stays.
// ---------------------------------------------------------------------------
__global__ __launch_bounds__(256, 2) void fft_corr(const float* __restrict__ q,
                                                   const float* __restrict__ k,
                                                   float2* __restrict__ Pc) {
    __shared__ float2 z0[LSEQ], z1[LSEQ];   // 32 KiB (swizzled)
    const int t    = threadIdx.x;
    const int bi   = blockIdx.x;            // 1024 = 8 xcd * 8 bh * 8 grp * 2 half
    const int xcd  = bi & 7;
    const int sl   = bi >> 3;               // 0..127
    const int bh   = xcd * 8 + (sl >> 4);   // 16 blocks of same bh share an XCD
    const int grp  = (sl >> 1) & 7;
    const int half = sl & 1;
    const int b    = bh >> 3;
    const int h    = bh & 7;
    const size_t base = (size_t)bh * LSEQ * ND + (size_t)(grp * 8 + half * 4);

    // twiddle power chains (per thread, shared by all channels)
    float2 WA[7], WB[7], WC[7];
    {
        float sn, cs;
        __sincosf(-6.28318530717958647692f * (float)t / 2048.f, &sn, &cs);
        WA[0] = make_float2(cs, sn);
        __sincosf(-6.28318530717958647692f * (float)(t & 31) / 256.f, &sn, &cs);
        WB[0] = make_float2(cs, sn);
        __sincosf(-6.28318530717958647692f * (float)(t & 3) / 32.f, &sn, &cs);
        WC[0] = make_float2(cs, sn);
        #pragma unroll
        for (int m = 1; m < 7; ++m) {
            WA[m] = CMUL(WA[m-1].x, WA[m-1].y, WA[0].x, WA[0].y);
            WB[m] = CMUL(WB[m-1].x, WB[m-1].y, WB[0].x, WB[0].y);
            WC[m] = CMUL(WC[m-1].x, WC[m-1].y, WC[0].x, WC[0].y);
        }
    }

    // owned product slots: cc in {0,1,4,5} -> f in [0,1024)
    int fS[4], pmS[4];
    #pragma unroll
    for (int s = 0; s < 4; ++s) {
        const int cc = (s < 2) ? s : s + 2;           // {0,1,4,5}
        const int f  = fofp(8 * t + cc);
        const int m  = (2048 - f) & 2047;
        fS[s]  = f;
        pmS[s] = SWZ(pof(m));
    }
    float aFr[4] = {0, 0, 0, 0}, aFi[4] = {0, 0, 0, 0};
    float aS = 0.f;                      // f=1024 special (thread 0)

    const int sbB   = (t >> 5) * 256 + (t & 31);
    const int baseC = (t >> 2) * 32 + (t & 3);
    int adrB[8], adrC[8], adrD[8];
    #pragma unroll
    for (int n = 0; n < 8; ++n) {
        adrB[n] = SWZ(sbB + 32 * n);
        adrC[n] = SWZ(baseC + 4 * n);
        adrD[n] = SWZ(8 * t + n);
    }

    float4 qa[8], ka[8];
    #pragma unroll
    for (int j = 0; j < 8; ++j) {
        const size_t r = base + (size_t)(t + 256 * j) * ND;
        qa[j] = *(const float4*)(q + r);
        ka[j] = *(const float4*)(k + r);
    }

    float2 X0[8], X1[8], Y0[8], Y1[8];

    // stage A for a channel pair (c0,c1): radix-8 from regs, scatter to bands
    auto stageA = [&](int c0, int c1) {
        #pragma unroll
        for (int j = 0; j < 8; ++j) {
            X0[j] = make_float2((&qa[j].x)[c0], (&ka[j].x)[c0]);
            X1[j] = make_float2((&qa[j].x)[c1], (&ka[j].x)[c1]);
        }
        dft8(X0, Y0);
        dft8(X1, Y1);
        #pragma unroll
        for (int m = 1; m < 8; ++m) {
            Y0[m] = CMUL(Y0[m].x, Y0[m].y, WA[m-1].x, WA[m-1].y);
            Y1[m] = CMUL(Y1[m].x, Y1[m].y, WA[m-1].x, WA[m-1].y);
        }
        #pragma unroll
        for (int m = 0; m < 8; ++m) {
            const int a = SWZ(m * 256 + t);
            z0[a] = Y0[m];
            z1[a] = Y1[m];
        }
    };
    // stages B,C,D back-to-back — intra-wave region, NO barriers inside
    auto stageBCD = [&]() {
        stageR8(z0, adrB, WB);
        stageR8(z1, adrB, WB);
        stageR8(z0, adrC, WC);
        stageR8(z1, adrC, WC);
        stageD(z0, adrD, X0);
        stageD(z1, adrD, X1);
    };
    // product: acc Q[f] conj(K[f]) for 4 owned slots (+f=1024)
    auto product = [&]() {
        #pragma unroll
        for (int s = 0; s < 4; ++s) {
            const int cc = (s < 2) ? s : s + 2;   // {0,1,4,5}
            {
                const float2 Zf = X0[cc], Zm = z0[pmS[s]];
                const float qr = 0.5f * (Zf.x + Zm.x), qi = 0.5f * (Zf.y - Zm.y);
                const float kr = 0.5f * (Zf.y + Zm.y), ki = 0.5f * (Zm.x - Zf.x);
                aFr[s] += qr * kr + qi * ki;
                aFi[s] += qi * kr - qr * ki;
            }
            {
                const float2 Zf = X1[cc], Zm = z1[pmS[s]];
                const float qr = 0.5f * (Zf.x + Zm.x), qi = 0.5f * (Zf.y - Zm.y);
                const float kr = 0.5f * (Zf.y + Zm.y), ki = 0.5f * (Zm.x - Zf.x);
                aFr[s] += qr * kr + qi * ki;
                aFi[s] += qi * kr - qr * ki;
            }
        }
        if (t == 0) aS += X0[2].x * X0[2].y + X1[2].x * X1[2].y;
    };

    // pr = 0 (no entry barrier — planes untouched at block start)
    stageA(0, 1);
    __syncthreads();                 // A scatter complete (cross-wave)
    stageBCD();
    __syncthreads();                 // D writeback complete (mirror reads)
    product();
    __syncthreads();                 // product reads done — planes reusable
    // pr = 1
    stageA(2, 3);
    __syncthreads();
    stageBCD();
    __syncthreads();
    product();

    // compact store: Pc[part][b][f] = acc, f = fS[s] in [0,1024).
    // slot 0 packs (Re S[0], Re S[1024]); Im S[0] is mathematically 0.
    const int part = h * 16 + grp * 2 + half;        // 0..127
    float2* Pp = Pc + (size_t)part * (NB * 1024) + (size_t)b * 1024;
    #pragma unroll
    for (int s = 0; s < 4; ++s) Pp[fS[s]] = make_float2(aFr[s], aFi[s]);
    if (t == 0) Pp[0] = make_float2(aFr[0], aS);
}

// ---------------------------------------------------------------------------
// Reduce 128 compact partials IN-PLACE into part 0. 128 blocks; XCD-ALIGNED:
// fft_corr writes all partials of batch b from XCD b, so mapping b=bi&7 puts
// every read on the local XCD's L2 (1 MB/batch, L2-resident).
// ---------------------------------------------------------------------------
__global__ __launch_bounds__(256) void reduce_S(float2* __restrict__ Pc) {
    __shared__ float2 acc[256];
    const int t     = threadIdx.x;
    const int bi    = blockIdx.x;                    // 128
    const int b     = bi & 7;                        // XCD-local batch
    const int seg   = bi >> 3;                       // 16 segments x 64 cols
    const int col   = b * 1024 + seg * 64 + (t & 63);
    const int slice = t >> 6;                        // 4 slices x 32 parts
    float ax = 0.f, ay = 0.f;
    #pragma unroll 8
    for (int pp = 0; pp < 32; ++pp) {
        const float2 v = Pc[(size_t)(slice * 32 + pp) * (NB * 1024) + col];
        ax += v.x; ay += v.y;
    }
    acc[t] = make_float2(ax, ay);
    __syncthreads();
    if (t < 64) {
        const float2 r0 = acc[t], r1 = acc[t + 64], r2 = acc[t + 128], r3 = acc[t + 192];
        Pc[col] = make_float2(r0.x + r1.x + r2.x + r3.x, r0.y + r1.y + r2.y + r3.y);
    }
}

// ---------------------------------------------------------------------------
// Kernel B: one 64-lane wave per batch, zero barriers, no LDS (round-5,
// verified). Register FFT of conj(S) via fft32_dif + twiddle + 6-stage shfl
// DIF; top-16 by 16 unrolled wave argmax rounds; softmax on lane 0.
// ---------------------------------------------------------------------------
__global__ __launch_bounds__(64) void ifft_topk(const float2* __restrict__ S,
                                                float* __restrict__ wout,
                                                int* __restrict__ dout) {
    const int b = blockIdx.x;
    const int L = threadIdx.x;                         // lane 0..63
    const int k2 = (int)(__brev((unsigned)L) >> 26);   // br6(L)
    const int base32 = k2 << 5;

    // ---- build x[f] = conj(S)[f], f = 64*j + L, from compact spectrum ----
    float2 z[32];
    #pragma unroll
    for (int j = 0; j < 32; ++j) {
        const int f   = 64 * j + L;
        const int idx = (f < 1024) ? f : ((f == 1024) ? 0 : 2048 - f);
        const float2 s = S[b * 1024 + idx];
        float2 x;
        if (f == 0)         x = make_float2(s.x, 0.f);     // S[0] real
        else if (f == 1024) x = make_float2(s.y, 0.f);     // S[1024] real (packed)
        else if (f < 1024)  x = make_float2(s.x, -s.y);    // conj(S[f])
        else                x = make_float2(s.x,  s.y);    // conj(S[f]) = S[2048-f]
        z[j] = x;
    }

    // ---- step 1: in-lane DIF-32 ----
    fft32_dif(z);

    // ---- step 2: twiddle w_2048^{L*k1}, k1 = BR5(p) ----
    {
        float sn, cs;
        __sincosf(-6.28318530717958647692f * (float)L / 2048.f, &sn, &cs);
        const float2 W1 = make_float2(cs, sn);
        float2 Wc = W1;
        z[BR5(1)] = cmulf(z[BR5(1)], Wc);
        #pragma unroll
        for (int m = 2; m < 32; ++m) {
            Wc = cmulf(Wc, W1);
            z[BR5(m)] = cmulf(z[BR5(m)], Wc);
        }
    }

    // ---- step 3: cross-lane DIF-64 over lanes (6 shfl_xor stages) ----
    #pragma unroll
    for (int s = 0; s < 6; ++s) {
        const int hh = 32 >> s;
        float ts, tc;
        __sincosf(-6.28318530717958647692f * (float)(L & (hh - 1)) /
                      (float)(64 >> s), &ts, &tc);
        const bool bot = (L & hh) != 0;
        #pragma unroll
        for (int p = 0; p < 32; ++p) {
            const float ex = __shfl_xor(z[p].x, hh);
            const float ey = __shfl_xor(z[p].y, hh);
            const float ax = z[p].x + ex, ay = z[p].y + ey;
            const float sx = ex - z[p].x, sy = ey - z[p].y;
            const float bx = sx * tc - sy * ts;
            const float by = sx * ts + sy * tc;
            z[p].x = bot ? bx : ax;
            z[p].y = bot ? by : ay;
        }
    }

    // ---- mc values: val[p] = Re/(L*H*D), tau(p) = BR5(p) + base32 ----
    const float scale = 1.0f / ((float)LSEQ * (float)(NH * ND));
    float vals[32];
    #pragma unroll
    for (int p = 0; p < 32; ++p) vals[p] = z[p].x * scale;

    // ---- top-16 by iterative wave-wide argmax (ties -> smaller tau) ----
    float topv[NDEL]; int topi[NDEL];
    #pragma unroll
    for (int it = 0; it < NDEL; ++it) {
        float bv = -3e38f; int btau = 1 << 30;
        #pragma unroll
        for (int p = 0; p < 32; ++p) {
            const int tau = BR5(p) + base32;
            if (vals[p] > bv || (vals[p] == bv && tau < btau)) { bv = vals[p]; btau = tau; }
        }
        #pragma unroll
        for (int off = 32; off; off >>= 1) {
            const float ov = __shfl_xor(bv, off);
            const int   ot = __shfl_xor(btau, off);
            if (ov > bv || (ov == bv && ot < btau)) { bv = ov; btau = ot; }
        }
        topv[it] = bv; topi[it] = btau;
        #pragma unroll
        for (int p = 0; p < 32; ++p)
            if (BR5(p) + base32 == btau) vals[p] = -3e38f;   // remove winner
    }

    if (L == 0) {
        const float m = topv[0];
        float e[NDEL], sum = 0.f;
        #pragma unroll
        for (int i = 0; i < NDEL; ++i) { e[i] = __expf(topv[i] - m); sum += e[i]; }
        const float inv = 1.0f / sum;
        #pragma unroll
        for (int i = 0; i < NDEL; ++i) {
            wout[b * NDEL + i] = e[i] * inv;
            dout[b * NDEL + i] = topi[i];
        }
    }
}

// ---------------------------------------------------------------------------
// Kernel C: out[b,h,t,d] = sum_k w[b,k] * v[b,h,(t+delay[b,k]) & 2047, d]
// XCD swizzle: 128 t-tiles of one (b,h) share an XCD (v slice L2-resident).
// ---------------------------------------------------------------------------
__global__ __launch_bounds__(256) void gather_out(const float* __restrict__ v,
                                                  const float* __restrict__ w,
                                                  const int* __restrict__ delay,
                                                  float* __restrict__ out) {
    const int bi  = blockIdx.x;          // 8192 = 64 bh * 128 tiles
    const int xcd = bi & 7;
    const int s   = bi >> 3;
    const int bh  = xcd * 8 + (s >> 7);
    const int bt  = s & 127;
    const int b   = bh >> 3;
    const int tid = threadIdx.x;

    __shared__ float sw_[NDEL];
    __shared__ int   sd_[NDEL];
    if (tid < NDEL) {
        sw_[tid] = w[b * NDEL + tid];
        sd_[tid] = delay[b * NDEL + tid];
    }
    __syncthreads();

    const float* vb = v + (size_t)bh * LSEQ * ND;
    float*       ob = out + (size_t)bh * LSEQ * ND;

    const int row = tid >> 4;
    const int col = (tid & 15) * 4;
    const int t   = bt * 16 + row;

    float4 acc = make_float4(0.f, 0.f, 0.f, 0.f);
    #pragma unroll
    for (int kk = 0; kk < NDEL; ++kk) {
        const int r = (t + sd_[kk]) & (LSEQ - 1);
        const float4 vv = *(const float4*)(vb + (size_t)r * ND + col);
        const float wv = sw_[kk];
        acc.x += wv * vv.x; acc.y += wv * vv.y;
        acc.z += wv * vv.z; acc.w += wv * vv.w;
    }
    *(float4*)(ob + (size_t)t * ND + col) = acc;
}

// ---------------------------------------------------------------------------
extern "C" void kernel_launch(void* const* d_in, const int* in_sizes, int n_in,
                              void* d_out, int out_size, void* d_ws, size_t ws_size,
                              hipStream_t stream) {
    const float* q = (const float*)d_in[0];
    const float* k = (const float*)d_in[1];
    const float* v = (const float*)d_in[2];
    float* out = (float*)d_out;

    float2* Pc    = (float2*)((char*)d_ws + WS_P_OFF);
    float*  w     = (float*)((char*)d_ws + WS_W_OFF);
    int*    delay = (int*)((char*)d_ws + WS_DELAY_OFF);

    fft_corr<<<dim3(1024), dim3(256), 0, stream>>>(q, k, Pc);
    reduce_S<<<dim3(128), dim3(256), 0, stream>>>(Pc);
    ifft_topk<<<dim3(NB), dim3(64), 0, stream>>>(Pc, w, delay);   // part 0 = S
    gather_out<<<dim3(NB * NH * 128), dim3(256), 0, stream>>>(v, w, delay, out);
}

// Round 7
// 201.232 us; speedup vs baseline: 1.1245x; 1.1133x over previous
//
#include <hip/hip_runtime.h>

// B=8, H=8, L=2048, D=64, num_delays=16
static constexpr int LSEQ = 2048;
static constexpr int NB   = 8;
static constexpr int NH   = 8;
static constexpr int ND   = 64;
static constexpr int NDEL = 16;

// ws layout (same 8.4 MB proven-safe envelope, same w/delay offsets):
//   Pc    : float2[128 part][8 b][1024]  at 0      (exactly 8 MiB)
//           compact partial spectra: slot j in [1,1024) holds freq j;
//           slot 0 packs (Re S[0], Re S[1024]) — both freqs are purely real.
//           After reduce_S, part 0 holds the reduced compact spectrum.
//   w     : float [8][16]               at 8388608
//   delay : int   [8][16]               at 8389120
static constexpr size_t WS_P_OFF     = 0;
static constexpr size_t WS_W_OFF     = 8388608;
static constexpr size_t WS_DELAY_OFF = 8389120;

// LDS bank swizzle on float2 index: fold bits 4..6 into bits 1..3.
// Touches only bits 1..3 — band bits (8..10) and 32-group bits (5..7) are
// preserved, which is what makes the intra-wave barrier elision legal.
__device__ __forceinline__ int SWZ(int x) { return x ^ (((x >> 4) & 7) << 1); }

// digit-reversed position of frequency f (radices 8,8,8,4 DIF) and inverse
__device__ __forceinline__ int pof(int f) {
    return ((f & 7) << 8) | (((f >> 3) & 7) << 5) | (((f >> 6) & 7) << 2) | (f >> 9);
}
__device__ __forceinline__ int fofp(int p) {
    return (p >> 8) | (((p >> 5) & 7) << 3) | (((p >> 2) & 7) << 6) | ((p & 3) << 9);
}

#define CMUL(ar, ai, br, bi) make_float2((ar)*(br) - (ai)*(bi), (ar)*(bi) + (ai)*(br))

// 8-pt DIF DFT in regs; x[0..7] in, X[0..7] (natural freq order) out.
__device__ __forceinline__ void dft8(const float2 x[8], float2 X[8]) {
    const float RH = 0.70710678118654752440f;
    float2 a0 = make_float2(x[0].x + x[4].x, x[0].y + x[4].y);
    float2 a1 = make_float2(x[1].x + x[5].x, x[1].y + x[5].y);
    float2 a2 = make_float2(x[2].x + x[6].x, x[2].y + x[6].y);
    float2 a3 = make_float2(x[3].x + x[7].x, x[3].y + x[7].y);
    float2 b0 = make_float2(x[0].x - x[4].x, x[0].y - x[4].y);
    float  t1r = x[1].x - x[5].x, t1i = x[1].y - x[5].y;
    float2 b1 = make_float2(RH * (t1r + t1i), RH * (t1i - t1r));       // * w8^1
    float  t2r = x[2].x - x[6].x, t2i = x[2].y - x[6].y;
    float2 b2 = make_float2(t2i, -t2r);                                // * -i
    float  t3r = x[3].x - x[7].x, t3i = x[3].y - x[7].y;
    float2 b3 = make_float2(RH * (t3i - t3r), -RH * (t3r + t3i));      // * w8^3
    float2 c0 = make_float2(a0.x + a2.x, a0.y + a2.y);
    float2 d0 = make_float2(a0.x - a2.x, a0.y - a2.y);
    float2 c1 = make_float2(a1.x + a3.x, a1.y + a3.y);
    float2 d1 = make_float2(a1.y - a3.y, -(a1.x - a3.x));              // * -i
    X[0] = make_float2(c0.x + c1.x, c0.y + c1.y);
    X[4] = make_float2(c0.x - c1.x, c0.y - c1.y);
    X[2] = make_float2(d0.x + d1.x, d0.y + d1.y);
    X[6] = make_float2(d0.x - d1.x, d0.y - d1.y);
    float2 e0 = make_float2(b0.x + b2.x, b0.y + b2.y);
    float2 f0 = make_float2(b0.x - b2.x, b0.y - b2.y);
    float2 e1 = make_float2(b1.x + b3.x, b1.y + b3.y);
    float2 f1 = make_float2(b1.y - b3.y, -(b1.x - b3.x));              // * -i
    X[1] = make_float2(e0.x + e1.x, e0.y + e1.y);
    X[5] = make_float2(e0.x - e1.x, e0.y - e1.y);
    X[3] = make_float2(f0.x + f1.x, f0.y + f1.y);
    X[7] = make_float2(f0.x - f1.x, f0.y - f1.y);
}

// 4-pt DFT: X[m] = sum_j x[j] (-i)^{jm}
__device__ __forceinline__ void dft4(const float2 x[4], float2 X[4]) {
    float2 s0 = make_float2(x[0].x + x[2].x, x[0].y + x[2].y);
    float2 s1 = make_float2(x[1].x + x[3].x, x[1].y + x[3].y);
    float2 d0 = make_float2(x[0].x - x[2].x, x[0].y - x[2].y);
    float2 d1 = make_float2(x[1].y - x[3].y, -(x[1].x - x[3].x));      // * -i
    X[0] = make_float2(s0.x + s1.x, s0.y + s1.y);
    X[2] = make_float2(s0.x - s1.x, s0.y - s1.y);
    X[1] = make_float2(d0.x + d1.x, d0.y + d1.y);
    X[3] = make_float2(d0.x - d1.x, d0.y - d1.y);
}

// in-place radix-8 stage with twiddle chain W on LDS plane zp
__device__ __forceinline__ void stageR8(float2* zp, const int adr[8], const float2 W[7]) {
    float2 X[8], Y[8];
    #pragma unroll
    for (int j = 0; j < 8; ++j) X[j] = zp[adr[j]];
    dft8(X, Y);
    #pragma unroll
    for (int m = 1; m < 8; ++m) Y[m] = CMUL(Y[m].x, Y[m].y, W[m-1].x, W[m-1].y);
    #pragma unroll
    for (int m = 0; m < 8; ++m) zp[adr[m]] = Y[m];
}

// final twiddle-free stage: two radix-4 on 8 consecutive; result also in X
__device__ __forceinline__ void stageD(float2* zp, const int adr[8], float2 X[8]) {
    float2 xin[8];
    #pragma unroll
    for (int j = 0; j < 8; ++j) xin[j] = zp[adr[j]];
    dft4(&xin[0], &X[0]);
    dft4(&xin[4], &X[4]);
    #pragma unroll
    for (int m = 0; m < 8; ++m) zp[adr[m]] = X[m];
}

// ---------------------------------------------------------------------------
// Kernel A: round-6 verified (51 µs): round-3 pipeline + intra-wave barrier
// elision (stages B,C,D operate on bands owned by 32-thread clusters ⊂ one
// wave; same-wave DS ops are program-ordered → no barriers inside BCD).
// 5 barriers/block. Compact partial store.
// ---------------------------------------------------------------------------
__global__ __launch_bounds__(256, 2) void fft_corr(const float* __restrict__ q,
                                                   const float* __restrict__ k,
                                                   float2* __restrict__ Pc) {
    __shared__ float2 z0[LSEQ], z1[LSEQ];   // 32 KiB (swizzled)
    const int t    = threadIdx.x;
    const int bi   = blockIdx.x;            // 1024 = 8 xcd * 8 bh * 8 grp * 2 half
    const int xcd  = bi & 7;
    const int sl   = bi >> 3;               // 0..127
    const int bh   = xcd * 8 + (sl >> 4);   // 16 blocks of same bh share an XCD
    const int grp  = (sl >> 1) & 7;
    const int half = sl & 1;
    const int b    = bh >> 3;
    const int h    = bh & 7;
    const size_t base = (size_t)bh * LSEQ * ND + (size_t)(grp * 8 + half * 4);

    // twiddle power chains (per thread, shared by all channels)
    float2 WA[7], WB[7], WC[7];
    {
        float sn, cs;
        __sincosf(-6.28318530717958647692f * (float)t / 2048.f, &sn, &cs);
        WA[0] = make_float2(cs, sn);
        __sincosf(-6.28318530717958647692f * (float)(t & 31) / 256.f, &sn, &cs);
        WB[0] = make_float2(cs, sn);
        __sincosf(-6.28318530717958647692f * (float)(t & 3) / 32.f, &sn, &cs);
        WC[0] = make_float2(cs, sn);
        #pragma unroll
        for (int m = 1; m < 7; ++m) {
            WA[m] = CMUL(WA[m-1].x, WA[m-1].y, WA[0].x, WA[0].y);
            WB[m] = CMUL(WB[m-1].x, WB[m-1].y, WB[0].x, WB[0].y);
            WC[m] = CMUL(WC[m-1].x, WC[m-1].y, WC[0].x, WC[0].y);
        }
    }

    // owned product slots: cc in {0,1,4,5} -> f in [0,1024)
    int fS[4], pmS[4];
    #pragma unroll
    for (int s = 0; s < 4; ++s) {
        const int cc = (s < 2) ? s : s + 2;           // {0,1,4,5}
        const int f  = fofp(8 * t + cc);
        const int m  = (2048 - f) & 2047;
        fS[s]  = f;
        pmS[s] = SWZ(pof(m));
    }
    float aFr[4] = {0, 0, 0, 0}, aFi[4] = {0, 0, 0, 0};
    float aS = 0.f;                      // f=1024 special (thread 0)

    const int sbB   = (t >> 5) * 256 + (t & 31);
    const int baseC = (t >> 2) * 32 + (t & 3);
    int adrB[8], adrC[8], adrD[8];
    #pragma unroll
    for (int n = 0; n < 8; ++n) {
        adrB[n] = SWZ(sbB + 32 * n);
        adrC[n] = SWZ(baseC + 4 * n);
        adrD[n] = SWZ(8 * t + n);
    }

    float4 qa[8], ka[8];
    #pragma unroll
    for (int j = 0; j < 8; ++j) {
        const size_t r = base + (size_t)(t + 256 * j) * ND;
        qa[j] = *(const float4*)(q + r);
        ka[j] = *(const float4*)(k + r);
    }

    float2 X0[8], X1[8], Y0[8], Y1[8];

    // stage A for a channel pair (c0,c1): radix-8 from regs, scatter to bands
    auto stageA = [&](int c0, int c1) {
        #pragma unroll
        for (int j = 0; j < 8; ++j) {
            X0[j] = make_float2((&qa[j].x)[c0], (&ka[j].x)[c0]);
            X1[j] = make_float2((&qa[j].x)[c1], (&ka[j].x)[c1]);
        }
        dft8(X0, Y0);
        dft8(X1, Y1);
        #pragma unroll
        for (int m = 1; m < 8; ++m) {
            Y0[m] = CMUL(Y0[m].x, Y0[m].y, WA[m-1].x, WA[m-1].y);
            Y1[m] = CMUL(Y1[m].x, Y1[m].y, WA[m-1].x, WA[m-1].y);
        }
        #pragma unroll
        for (int m = 0; m < 8; ++m) {
            const int a = SWZ(m * 256 + t);
            z0[a] = Y0[m];
            z1[a] = Y1[m];
        }
    };
    // stages B,C,D back-to-back — intra-wave region, NO barriers inside
    auto stageBCD = [&]() {
        stageR8(z0, adrB, WB);
        stageR8(z1, adrB, WB);
        stageR8(z0, adrC, WC);
        stageR8(z1, adrC, WC);
        stageD(z0, adrD, X0);
        stageD(z1, adrD, X1);
    };
    // product: acc Q[f] conj(K[f]) for 4 owned slots (+f=1024)
    auto product = [&]() {
        #pragma unroll
        for (int s = 0; s < 4; ++s) {
            const int cc = (s < 2) ? s : s + 2;   // {0,1,4,5}
            {
                const float2 Zf = X0[cc], Zm = z0[pmS[s]];
                const float qr = 0.5f * (Zf.x + Zm.x), qi = 0.5f * (Zf.y - Zm.y);
                const float kr = 0.5f * (Zf.y + Zm.y), ki = 0.5f * (Zm.x - Zf.x);
                aFr[s] += qr * kr + qi * ki;
                aFi[s] += qi * kr - qr * ki;
            }
            {
                const float2 Zf = X1[cc], Zm = z1[pmS[s]];
                const float qr = 0.5f * (Zf.x + Zm.x), qi = 0.5f * (Zf.y - Zm.y);
                const float kr = 0.5f * (Zf.y + Zm.y), ki = 0.5f * (Zm.x - Zf.x);
                aFr[s] += qr * kr + qi * ki;
                aFi[s] += qi * kr - qr * ki;
            }
        }
        if (t == 0) aS += X0[2].x * X0[2].y + X1[2].x * X1[2].y;
    };

    // pr = 0 (no entry barrier — planes untouched at block start)
    stageA(0, 1);
    __syncthreads();                 // A scatter complete (cross-wave)
    stageBCD();
    __syncthreads();                 // D writeback complete (mirror reads)
    product();
    __syncthreads();                 // product reads done — planes reusable
    // pr = 1
    stageA(2, 3);
    __syncthreads();
    stageBCD();
    __syncthreads();
    product();

    // compact store: Pc[part][b][f] = acc, f = fS[s] in [0,1024).
    // slot 0 packs (Re S[0], Re S[1024]); Im S[0] is mathematically 0.
    const int part = h * 16 + grp * 2 + half;        // 0..127
    float2* Pp = Pc + (size_t)part * (NB * 1024) + (size_t)b * 1024;
    #pragma unroll
    for (int s = 0; s < 4; ++s) Pp[fS[s]] = make_float2(aFr[s], aFi[s]);
    if (t == 0) Pp[0] = make_float2(aFr[0], aS);
}

// ---------------------------------------------------------------------------
// Reduce 128 compact partials IN-PLACE into part 0. 128 blocks; XCD-ALIGNED
// (round-6): all partials of batch b were written from XCD b; b = bi&7 keeps
// every read on the local XCD's L2.
// ---------------------------------------------------------------------------
__global__ __launch_bounds__(256) void reduce_S(float2* __restrict__ Pc) {
    __shared__ float2 acc[256];
    const int t     = threadIdx.x;
    const int bi    = blockIdx.x;                    // 128
    const int b     = bi & 7;                        // XCD-local batch
    const int seg   = bi >> 3;                       // 16 segments x 64 cols
    const int col   = b * 1024 + seg * 64 + (t & 63);
    const int slice = t >> 6;                        // 4 slices x 32 parts
    float ax = 0.f, ay = 0.f;
    #pragma unroll 8
    for (int pp = 0; pp < 32; ++pp) {
        const float2 v = Pc[(size_t)(slice * 32 + pp) * (NB * 1024) + col];
        ax += v.x; ay += v.y;
    }
    acc[t] = make_float2(ax, ay);
    __syncthreads();
    if (t < 64) {
        const float2 r0 = acc[t], r1 = acc[t + 64], r2 = acc[t + 128], r3 = acc[t + 192];
        Pc[col] = make_float2(r0.x + r1.x + r2.x + r3.x, r0.y + r1.y + r2.y + r3.y);
    }
}

// ---------------------------------------------------------------------------
// Kernel B: 256-thread verified FFT pipeline (round-3) + intra-wave elision
// on B/C/D (round-6 proven) + PER-WAVE register top-16 (no barriers in the
// argmax loop). Each wave owns 512 taus in 8 regs/lane; 16 shfl-only argmax
// rounds produce a descending list; one barrier; thread 0 merges the 4
// descending lists and does softmax. Barriers: ~37 -> 6.
// ---------------------------------------------------------------------------
__global__ __launch_bounds__(256) void ifft_topk(const float2* __restrict__ S,
                                                 float* __restrict__ wout,
                                                 int* __restrict__ dout) {
    __shared__ float2 zz[LSEQ];          // 16 KiB work (swizzled in stages)
    __shared__ float  mc[LSEQ];          // 8 KiB, natural tau order
    __shared__ float  candv[4][NDEL];
    __shared__ int    candt[4][NDEL];
    const int b = blockIdx.x, t = threadIdx.x;

    float2 WA[7], WB[7], WC[7];
    {
        float sn, cs;
        __sincosf(-6.28318530717958647692f * (float)t / 2048.f, &sn, &cs);
        WA[0] = make_float2(cs, sn);
        __sincosf(-6.28318530717958647692f * (float)(t & 31) / 256.f, &sn, &cs);
        WB[0] = make_float2(cs, sn);
        __sincosf(-6.28318530717958647692f * (float)(t & 3) / 32.f, &sn, &cs);
        WC[0] = make_float2(cs, sn);
        #pragma unroll
        for (int m = 1; m < 7; ++m) {
            WA[m] = CMUL(WA[m-1].x, WA[m-1].y, WA[0].x, WA[0].y);
            WB[m] = CMUL(WB[m-1].x, WB[m-1].y, WB[0].x, WB[0].y);
            WC[m] = CMUL(WC[m-1].x, WC[m-1].y, WC[0].x, WC[0].y);
        }
    }
    const int sbB   = (t >> 5) * 256 + (t & 31);
    const int baseC = (t >> 2) * 32 + (t & 3);
    int adrB[8], adrC[8], adrD[8];
    #pragma unroll
    for (int n = 0; n < 8; ++n) {
        adrB[n] = SWZ(sbB + 32 * n);
        adrC[n] = SWZ(baseC + 4 * n);
        adrD[n] = SWZ(8 * t + n);
    }

    // load compact spectrum, reconstruct full digit-rev spectrum in zz:
    // freq j -> slot pof(j); freq 2048-j -> conj at slot pof(2048-j).
    #pragma unroll
    for (int u = 0; u < 4; ++u) {
        const int j = t + 256 * u;
        const float2 s = S[b * 1024 + j];
        if (j == 0) {
            zz[0] = make_float2(s.x, 0.f);            // pof(0)    = 0
            zz[2] = make_float2(s.y, 0.f);            // pof(1024) = 2
        } else {
            zz[pof(j)]        = s;
            zz[pof(2048 - j)] = make_float2(s.x, -s.y);
        }
    }
    __syncthreads();

    // gather stage-A operands: x[f] = conj(S[f]) at slot pof(f), f = t+256j
    float2 X[8], Y[8];
    #pragma unroll
    for (int j = 0; j < 8; ++j) {
        const float2 s = zz[pof(t + 256 * j)];
        X[j] = make_float2(s.x, -s.y);
    }
    __syncthreads();                     // all gathers done before scatter

    dft8(X, Y);
    #pragma unroll
    for (int m = 1; m < 8; ++m) Y[m] = CMUL(Y[m].x, Y[m].y, WA[m-1].x, WA[m-1].y);
    #pragma unroll
    for (int m = 0; m < 8; ++m) zz[SWZ(m * 256 + t)] = Y[m];
    __syncthreads();

    // B, C, D: intra-wave region (band t>>5 owned by the 32-cluster) — no
    // barriers (round-6 proof carried over; same addressing, same SWZ).
    stageR8(zz, adrB, WB);
    stageR8(zz, adrC, WC);
    {
        float2 xin[8];
        #pragma unroll
        for (int j = 0; j < 8; ++j) xin[j] = zz[adrD[j]];
        dft4(&xin[0], &X[0]);
        dft4(&xin[4], &X[4]);
    }

    // mc[tau] = Re(out)/(L*H*D); slot 8t+cc holds tau = fofp(8t+cc)
    const float scale = 1.0f / ((float)LSEQ * (float)(NH * ND));
    #pragma unroll
    for (int cc = 0; cc < 8; ++cc) mc[fofp(8 * t + cc)] = X[cc].x * scale;
    __syncthreads();

    // ---- per-wave top-16 (wave w owns taus [512w, 512w+512), 8 regs/lane) --
    const int L = t & 63, wv = t >> 6;
    float v[8];
    #pragma unroll
    for (int u = 0; u < 8; ++u) v[u] = mc[512 * wv + 64 * u + L];

    for (int it = 0; it < NDEL; ++it) {
        // local argmax over 8 (ascending u = ascending tau -> ties keep smaller)
        float bv = v[0]; int bu = 0;
        #pragma unroll
        for (int u = 1; u < 8; ++u) if (v[u] > bv) { bv = v[u]; bu = u; }
        int bt_ = 512 * wv + 64 * bu + L;
        // wave-wide shfl reduce (ties -> smaller tau)
        #pragma unroll
        for (int off = 32; off; off >>= 1) {
            const float ov = __shfl_xor(bv, off);
            const int   ot = __shfl_xor(bt_, off);
            if (ov > bv || (ov == bv && ot < bt_)) { bv = ov; bt_ = ot; }
        }
        // owner lane clears the winner (static reg indexing)
        #pragma unroll
        for (int u = 0; u < 8; ++u)
            if (512 * wv + 64 * u + L == bt_) v[u] = -3e38f;
        if (L == 0) { candv[wv][it] = bv; candt[wv][it] = bt_; }
    }
    __syncthreads();

    // ---- merge 4 descending lists + softmax (thread 0) ----
    if (t == 0) {
        int hp[4] = {0, 0, 0, 0};
        float topv[NDEL]; int topi[NDEL];
        for (int it = 0; it < NDEL; ++it) {
            float bv = -3e38f; int bt_ = 1 << 30; int bw = 0;
            #pragma unroll
            for (int ww = 0; ww < 4; ++ww) {
                const float cv = candv[ww][hp[ww]];
                const int   ct = candt[ww][hp[ww]];
                if (cv > bv || (cv == bv && ct < bt_)) { bv = cv; bt_ = ct; bw = ww; }
            }
            topv[it] = bv; topi[it] = bt_; ++hp[bw];
        }
        const float m = topv[0];
        float e[NDEL], sum = 0.f;
        for (int i = 0; i < NDEL; ++i) { e[i] = __expf(topv[i] - m); sum += e[i]; }
        const float inv = 1.0f / sum;
        for (int i = 0; i < NDEL; ++i) {
            wout[b * NDEL + i] = e[i] * inv;
            dout[b * NDEL + i] = topi[i];
        }
    }
}

// ---------------------------------------------------------------------------
// Kernel C: out[b,h,t,d] = sum_k w[b,k] * v[b,h,(t+delay[b,k]) & 2047, d]
// XCD swizzle keeps each (b,h) v-slice L2-resident. out is write-once ->
// NONTEMPORAL stores so 16 MB of streaming writes don't evict the 16x-reused
// v slices from L2.
// ---------------------------------------------------------------------------
typedef float f4nt __attribute__((ext_vector_type(4)));

__global__ __launch_bounds__(256) void gather_out(const float* __restrict__ v,
                                                  const float* __restrict__ w,
                                                  const int* __restrict__ delay,
                                                  float* __restrict__ out) {
    const int bi  = blockIdx.x;          // 8192 = 64 bh * 128 tiles
    const int xcd = bi & 7;
    const int s   = bi >> 3;
    const int bh  = xcd * 8 + (s >> 7);
    const int bt  = s & 127;
    const int b   = bh >> 3;
    const int tid = threadIdx.x;

    __shared__ float sw_[NDEL];
    __shared__ int   sd_[NDEL];
    if (tid < NDEL) {
        sw_[tid] = w[b * NDEL + tid];
        sd_[tid] = delay[b * NDEL + tid];
    }
    __syncthreads();

    const float* vb = v + (size_t)bh * LSEQ * ND;
    float*       ob = out + (size_t)bh * LSEQ * ND;

    const int row = tid >> 4;
    const int col = (tid & 15) * 4;
    const int t   = bt * 16 + row;

    float4 acc = make_float4(0.f, 0.f, 0.f, 0.f);
    #pragma unroll
    for (int kk = 0; kk < NDEL; ++kk) {
        const int r = (t + sd_[kk]) & (LSEQ - 1);
        const float4 vv = *(const float4*)(vb + (size_t)r * ND + col);
        const float wv = sw_[kk];
        acc.x += wv * vv.x; acc.y += wv * vv.y;
        acc.z += wv * vv.z; acc.w += wv * vv.w;
    }
    f4nt val = {acc.x, acc.y, acc.z, acc.w};
    __builtin_nontemporal_store(val, (f4nt*)(ob + (size_t)t * ND + col));
}

// ---------------------------------------------------------------------------
extern "C" void kernel_launch(void* const* d_in, const int* in_sizes, int n_in,
                              void* d_out, int out_size, void* d_ws, size_t ws_size,
                              hipStream_t stream) {
    const float* q = (const float*)d_in[0];
    const float* k = (const float*)d_in[1];
    const float* v = (const float*)d_in[2];
    float* out = (float*)d_out;

    float2* Pc    = (float2*)((char*)d_ws + WS_P_OFF);
    float*  w     = (float*)((char*)d_ws + WS_W_OFF);
    int*    delay = (int*)((char*)d_ws + WS_DELAY_OFF);

    fft_corr<<<dim3(1024), dim3(256), 0, stream>>>(q, k, Pc);
    reduce_S<<<dim3(128), dim3(256), 0, stream>>>(Pc);
    ifft_topk<<<dim3(NB), dim3(256), 0, stream>>>(Pc, w, delay);  // part 0 = S
    gather_out<<<dim3(NB * NH * 128), dim3(256), 0, stream>>>(v, w, delay, out);
}